// Round 17
// baseline (243.931 us; speedup 1.0000x reference)
//
#include <hip/hip_runtime.h>
#include <math.h>

// Problem constants
constexpr int cB = 48, cN = 512, cIN = 400;
constexpr int cENC = 256, cHID = 128, cOUT = 128, cNREL = 53;
constexpr int cKNN = 10;
constexpr float cVSN = 1e-12f;
constexpr float cEPS = 0.3f;

constexpr int KP = 416;                        // cIN padded to multiple of 32
constexpr size_t ARRSZ = (size_t)cB * cN * KP; // elems per f16 array
constexpr int NBN = cB * cN;                   // 24576 rows
constexpr size_t NADJ = (size_t)cB * cN * cN;  // 12,582,912
constexpr size_t NE1 = (size_t)NBN * 128;      // 3,145,728

typedef _Float16 f16;
typedef _Float16 f16x8 __attribute__((ext_vector_type(8)));
typedef float f32x4 __attribute__((ext_vector_type(4)));

__device__ inline void gload16(const void* g, void* l) {
    __builtin_amdgcn_global_load_lds(
        (const __attribute__((address_space(1))) unsigned int*)g,
        (__attribute__((address_space(3))) unsigned int*)l, 16, 0, 0);
}

#define MFMA16(a, b, c) __builtin_amdgcn_mfma_f32_16x16x32_f16((a), (b), (c), 0, 0, 0)

// ---------------- K0: weight prep + fused split/norms ----------------
// blocks [0, KP]: weight prep; blocks (KP, KP+NBN/4]: X -> XH/XL + norms + mask
__global__ __launch_bounds__(256) void k_prep0(
    const float* __restrict__ X, const int* __restrict__ lens,
    const float* __restrict__ glw,
    const float* __restrict__ w_enc, const float* __restrict__ w1,
    const float* __restrict__ b_enc, const float* __restrict__ w2,
    f16* __restrict__ XH, f16* __restrict__ XL,
    float* __restrict__ maskA, float* __restrict__ invnM,
    f16* __restrict__ wc1H, float* __restrict__ bc1p, f16* __restrict__ w2tH)
{
    int bid = blockIdx.x;
    int t = threadIdx.x;
    if (bid <= KP) {
        int d = bid;
        __shared__ float wred[2][128];
        int o = t & 127, half = t >> 7;
        if (d < cIN) {
            float acc = 0.f;
            const float* we = w_enc + (size_t)d * cENC + half * 128;
            const float* w1p = w1 + (size_t)half * 128 * cHID + o;
            #pragma unroll 8
            for (int e = 0; e < 128; ++e) acc += we[e] * w1p[(size_t)e * cHID];
            wred[half][o] = acc;
            __syncthreads();
            if (half == 0) wc1H[(size_t)o * KP + d] = (f16)(wred[0][o] + wred[1][o]);
        } else if (d < KP) {
            if (t < 128) wc1H[(size_t)o * KP + d] = (f16)0.f;
        } else {
            float acc = 0.f;
            const float* w1p = w1 + (size_t)half * 128 * cHID + o;
            #pragma unroll 8
            for (int e = 0; e < 128; ++e) acc += b_enc[half * 128 + e] * w1p[(size_t)e * cHID];
            wred[half][o] = acc;
            __syncthreads();
            if (half == 0) bc1p[o] = wred[0][o] + wred[1][o];
        }
        if (d < cHID && t < 128) w2tH[(size_t)t * cHID + d] = (f16)w2[(size_t)d * cOUT + t];
        return;
    }
    // ---- fused split + norms: 4 rows per block, 1 wave per row ----
    int row = (bid - (KP + 1)) * 4 + (t >> 6);
    int lane = t & 63;
    int b = row >> 9, n = row & (cN - 1);
    const float* x = X + (size_t)row * cIN;
    bool act = lane < 50;
    int k = lane * 8;
    float4 z4 = make_float4(0.f, 0.f, 0.f, 0.f);
    float4 xa = act ? *(const float4*)&x[k]     : z4;
    float4 xb = act ? *(const float4*)&x[k + 4] : z4;
    float xv[8] = {xa.x, xa.y, xa.z, xa.w, xb.x, xb.y, xb.z, xb.w};
    float s[4] = {0.f, 0.f, 0.f, 0.f};
    #pragma unroll
    for (int p = 0; p < 4; ++p) {
        float4 ga = act ? *(const float4*)&glw[p * cIN + k]     : z4;
        float4 gb = act ? *(const float4*)&glw[p * cIN + k + 4] : z4;
        float gv[8] = {ga.x, ga.y, ga.z, ga.w, gb.x, gb.y, gb.z, gb.w};
        #pragma unroll
        for (int e = 0; e < 8; ++e) {
            float tt = xv[e] * gv[e];
            s[p] += tt * tt;
        }
    }
    f16x8 vh, vl;
    #pragma unroll
    for (int e = 0; e < 8; ++e) {
        f16 hh = (f16)xv[e];
        vh[e] = hh;
        vl[e] = (f16)(xv[e] - (float)hh);
    }
    if (lane < 52) {                  // lanes 50/51 write pad zeros (xv==0 there)
        *(f16x8*)(XH + (size_t)row * KP + k) = vh;
        *(f16x8*)(XL + (size_t)row * KP + k) = vl;
    }
    #pragma unroll
    for (int off = 32; off; off >>= 1) {
        s[0] += __shfl_xor(s[0], off, 64);
        s[1] += __shfl_xor(s[1], off, 64);
        s[2] += __shfl_xor(s[2], off, 64);
        s[3] += __shfl_xor(s[3], off, 64);
    }
    if (lane == 0) {
        float m = (n < lens[b]) ? 1.0f : 0.0f;
        float4 iv;
        iv.x = m / fmaxf(sqrtf(s[0]), cVSN);
        iv.y = m / fmaxf(sqrtf(s[1]), cVSN);
        iv.z = m / fmaxf(sqrtf(s[2]), cVSN);
        iv.w = m / fmaxf(sqrtf(s[3]), cVSN);
        *(float4*)&invnM[(size_t)row * 4] = iv;
        maskA[row] = m;
    }
}

// ---------------- K1: MFMA similarity; symmetric tiles + XCD-swizzle + 2-buf ------
__global__ __launch_bounds__(256, 3) void k_sim_mfma(
    const f16* __restrict__ XH, const f16* __restrict__ XL,
    const float* __restrict__ glw, const int* __restrict__ lens,
    const float* __restrict__ maskA, const float* __restrict__ invnM,
    float* __restrict__ G0, f16* __restrict__ RAh)
{
    // bijective XCD swizzle: all 64 blocks of a batch on one XCD (L2 holds its X panels)
    int L = blockIdx.x + (blockIdx.y << 3) + (blockIdx.z << 6);
    int xcd = L & 7, j0 = L >> 3;
    int work = xcd * 384 + j0;
    const int b = work >> 6;
    int rem = work & 63;
    const int n0 = (rem >> 3) * 64, m0 = (rem & 7) * 64;

    const int t = threadIdx.x;
    const int w = t >> 6, lane = t & 63;
    const int wr = w >> 1, wc = w & 1;
    const int lr = lane & 15, lc = lane >> 4;

    const size_t rowBaseB = (size_t)b * cN;
    const int len = lens[b];

    // symmetry: only tiles with n0 <= m0; masked tiles: pure no-op
    if (n0 >= len || m0 >= len || n0 > m0) return;

    __shared__ f16 lds[2][8192];   // 2 bufs x 4 tiles x [64 rows][4 slots][8 f16]
    __shared__ f16 w2l[4][KP];

    for (int i = t; i < 4 * KP; i += 256) {
        int p = i / KP, d = i - p * KP;
        float g = (d < cIN) ? glw[p * cIN + d] : 0.f;
        w2l[p][d] = (f16)(g * g);
    }

    f32x4 accG[2][2], accP[4][2][2];
    #pragma unroll
    for (int i = 0; i < 2; ++i)
        #pragma unroll
        for (int jj = 0; jj < 2; ++jj) {
            accG[i][jj] = (f32x4)0.f;
            #pragma unroll
            for (int p = 0; p < 4; ++p) accP[p][i][jj] = (f32x4)0.f;
        }

    constexpr int NPAN = KP / 32;    // 13

    // tiles: 0 = XH@n0, 1 = XL@n0, 2 = XH@m0, 3 = XL@m0; 4 gloads per wave per panel
#define SIM_STAGE(buf, pan) do { \
    const int kk0_ = (pan) * 32; \
    _Pragma("unroll") \
    for (int q = 0; q < 4; ++q) { \
        int c_ = w + q * 4;               /* chunk 0..15, wave-uniform */ \
        int tt_ = c_ >> 2, rq_ = c_ & 3; \
        int row_ = rq_ * 16 + (lane >> 2); \
        int kcg_ = (lane & 3) ^ (row_ & 3) ^ ((row_ >> 2) & 3); \
        const f16* arr_ = (tt_ & 1) ? XL : XH; \
        int rb_ = (tt_ < 2) ? n0 : m0; \
        const f16* g_ = arr_ + (rowBaseB + rb_ + row_) * (size_t)KP + kk0_ + kcg_ * 8; \
        gload16(g_, (void*)&lds[buf][tt_ * 2048 + rq_ * 512]); \
    } \
} while (0)

    SIM_STAGE(0, 0);
    __syncthreads();

    for (int pan = 0; pan < NPAN; ++pan) {
        int cur = pan & 1;
        if (pan + 1 < NPAN) SIM_STAGE(cur ^ 1, pan + 1);
        const f16x8* L8 = (const f16x8*)lds[cur];
        const int kk0 = pan * 32;
        f16x8 aH[2], aL[2], bH[2], bL[2], wp[4];
        #pragma unroll
        for (int i = 0; i < 2; ++i) {
            int r = wr * 32 + i * 16 + lr;
            int cell = r * 4 + (lc ^ (r & 3) ^ ((r >> 2) & 3));
            aH[i] = L8[cell];
            aL[i] = L8[256 + cell];
        }
        #pragma unroll
        for (int jj = 0; jj < 2; ++jj) {
            int r = wc * 32 + jj * 16 + lr;
            int cell = r * 4 + (lc ^ (r & 3) ^ ((r >> 2) & 3));
            bH[jj] = L8[512 + cell];
            bL[jj] = L8[768 + cell];
        }
        #pragma unroll
        for (int p = 0; p < 4; ++p) wp[p] = *(const f16x8*)&w2l[p][kk0 + lc * 8];

        __builtin_amdgcn_s_setprio(1);
        #pragma unroll
        for (int i = 0; i < 2; ++i)
            #pragma unroll
            for (int jj = 0; jj < 2; ++jj) {
                accG[i][jj] = MFMA16(aH[i], bH[jj], accG[i][jj]);
                accG[i][jj] = MFMA16(aH[i], bL[jj], accG[i][jj]);
                accG[i][jj] = MFMA16(aL[i], bH[jj], accG[i][jj]);
            }
        #pragma unroll
        for (int p = 0; p < 4; ++p)
            #pragma unroll
            for (int i = 0; i < 2; ++i) {
                f16x8 ap = aH[i] * wp[p];
                #pragma unroll
                for (int jj = 0; jj < 2; ++jj)
                    accP[p][i][jj] = MFMA16(ap, bH[jj], accP[p][i][jj]);
            }
        __builtin_amdgcn_s_setprio(0);
        __syncthreads();
    }
#undef SIM_STAGE

    // ---- epilogue: normalize, direct store; off-diag also stash for transpose ----
    float* sG = (float*)lds;             // [64][65] f32 = 16.6 KB
    f16*   sR = (f16*)((float*)lds + 64 * 65);  // [64][66] f16 = 8.4 KB  (25 KB <= 32 KB)
    const bool offdiag = (n0 != m0);

    #pragma unroll
    for (int i = 0; i < 2; ++i) {
        #pragma unroll
        for (int jj = 0; jj < 2; ++jj) {
            int ml = wc * 32 + jj * 16 + lr;
            int m = m0 + ml;
            size_t rowm = rowBaseB + m;
            float mskm = maskA[rowm];
            float4 im = *(const float4*)&invnM[rowm * 4];
            #pragma unroll
            for (int v = 0; v < 4; ++v) {
                int nl = wr * 32 + i * 16 + lc * 4 + v;
                size_t rown = rowBaseB + n0 + nl;
                float4 in_ = *(const float4*)&invnM[rown * 4];
                float g = accG[i][jj][v] * maskA[rown] * mskm;
                float s = 0.25f * (accP[0][i][jj][v] * in_.x * im.x
                                 + accP[1][i][jj][v] * in_.y * im.y
                                 + accP[2][i][jj][v] * in_.z * im.z
                                 + accP[3][i][jj][v] * in_.w * im.w);
                float rv = (s > cEPS) ? s : 0.f;
                __builtin_nontemporal_store(g, &G0[rown * cN + m]);
                RAh[rown * cN + m] = (f16)rv;
                if (offdiag) {
                    sG[nl * 65 + ml] = g;
                    sR[nl * 66 + ml] = (f16)rv;
                }
            }
        }
    }
    if (offdiag) {
        __syncthreads();
        // transpose-copy: G0[m][n] = G0[n][m], RA likewise (both symmetric)
        #pragma unroll
        for (int e = 0; e < 16; ++e) {
            int idx = t + e * 256;          // 0..4095
            int mr = idx >> 6, nc = idx & 63;
            size_t rowm = rowBaseB + m0 + mr;
            float gv = sG[nc * 65 + mr];
            f16 rvv = sR[nc * 66 + mr];
            __builtin_nontemporal_store(gv, &G0[rowm * cN + n0 + nc]);
            RAh[rowm * cN + n0 + nc] = rvv;
        }
    }
}

// ---------------- K2: per-row top-10, value-only; len-trimmed reads ----------------
__global__ void k_topk(const float* __restrict__ G0, const float* __restrict__ mask,
                       const int* __restrict__ lens,
                       int* __restrict__ kidx, float* __restrict__ rinv)
{
    int row = blockIdx.x * 4 + (threadIdx.x >> 6);
    int lane = threadIdx.x & 63;
    int b = row >> 9, n = row & (cN - 1);
    int len = lens[b];
    if (n >= len) {
        if (lane < cKNN) kidx[row * cKNN + lane] = lane;
        if (lane == 0) rinv[row] = 0.f;
        return;
    }
    int lenc = (len + 63) & ~63;
    const float* g = G0 + (long long)row * cN;
    float val[8];
    #pragma unroll
    for (int k = 0; k < 8; ++k) {
        int col = lane + 64 * k;
        val[k] = (col < lenc) ? __builtin_nontemporal_load(&g[col]) : -INFINITY;
    }
    float cnt = 0.f;
    long long mbase = (long long)b * cN;
    for (int r = 0; r < cKNN; ++r) {
        float best = val[0];
        #pragma unroll
        for (int k = 1; k < 8; ++k) best = fmaxf(best, val[k]);
        #pragma unroll
        for (int off = 32; off; off >>= 1) best = fmaxf(best, __shfl_xor(best, off, 64));
        int sl = -1;
        #pragma unroll
        for (int k = 7; k >= 0; --k) if (val[k] == best) sl = k;
        unsigned long long holders = __ballot(sl >= 0);
        int src = (int)(__ffsll((long long)holders) - 1);
        int mycol = lane + (sl << 6);
        int col = __shfl(mycol, src, 64);
        if (lane == src) val[sl] = -INFINITY;
        if (lane == 0) {
            kidx[row * cKNN + r] = col;
            cnt += mask[mbase + col];
        }
    }
    if (lane == 0) rinv[row] = rsqrtf(fmaxf(cnt, cVSN));
}

// ---------------- K3: adjacency assembly; masked rows/cols exact-zero paths --------
__global__ void k_adj2(const f16* __restrict__ RAh, const float* __restrict__ rinv,
                       const int* __restrict__ kidx, const int* __restrict__ lens,
                       f16* __restrict__ adjH, float* __restrict__ adjrs)
{
    int row = blockIdx.x;
    int t = threadIdx.x;  // 256
    int b = row >> 9, n = row & (cN - 1);
    int len = lens[b];
    long long base = (long long)row * cN;
    if (n >= len) {
        adjH[base + t] = (f16)0.f;
        adjH[base + t + 256] = (f16)0.f;
        if (t == 0) adjrs[row] = 0.f;
        return;
    }
    int w = t >> 6, lane = t & 63;
    __shared__ int sidx[cKNN];
    __shared__ float srv[cKNN];
    __shared__ float red[4];
    long long bbase = (long long)(row & ~(cN - 1));
    if (t < cKNN) {
        int c = kidx[row * cKNN + t];
        sidx[t] = c;
        srv[t] = rinv[bbase + c];
    }
    float ra0 = (t < len) ? (float)RAh[base + t] : 0.f;
    float ra1 = (t + 256 < len) ? (float)RAh[base + t + 256] : 0.f;
    float s = ra0 + ra1;
    #pragma unroll
    for (int off = 32; off; off >>= 1) s += __shfl_xor(s, off, 64);
    if (lane == 0) red[w] = s;
    __syncthreads();
    float rsum = red[0] + red[1] + red[2] + red[3];
    float inv_rs = 1.0f / fmaxf(rsum, cVSN);
    float rn = rinv[row];
    float osum = 0.f;
    #pragma unroll
    for (int mi = 0; mi < 2; ++mi) {
        int m = t + mi * 256;
        float ra = mi ? ra1 : ra0;
        float v = 0.2f * ra * inv_rs;
        #pragma unroll
        for (int k = 0; k < cKNN; ++k)
            if (m == sidx[k]) v += 0.8f * rn * srv[k];
        adjH[base + m] = (f16)v;
        osum += v;
    }
    #pragma unroll
    for (int off = 32; off; off >>= 1) osum += __shfl_xor(osum, off, 64);
    __syncthreads();
    if (lane == 0) red[w] = osum;
    __syncthreads();
    if (t == 0) adjrs[row] = red[0] + red[1] + red[2] + red[3];
}

// ---------------- Single-pass f16 MFMA GEMM; ADJA enables mask-driven trimming ----
template<int BIAS, bool RELU, int OMODE, bool ADJA>
__global__ __launch_bounds__(256, 4) void k_gemm1(
    const f16* __restrict__ A, const f16* __restrict__ Bp,
    long long bStrideB, int K, const int* __restrict__ lens,
    const float* __restrict__ biasv, const float* __restrict__ bc1p,
    const float* __restrict__ adjrs, const int* __restrict__ ments,
    f16* __restrict__ CH, float* __restrict__ part)
{
    int L = blockIdx.x + blockIdx.y * gridDim.x;
    int work = (L & 7) * 96 + (L >> 3);
    const int R0 = (work >> 1) * 64;
    const int bn0 = (work & 1) * 64;
    const int bidx = R0 >> 9;
    const int t = threadIdx.x, w = t >> 6, lane = t & 63;
    const int wr = w >> 1, wc = w & 1, lr = lane & 15, lc = lane >> 4;
    __shared__ f16 lds[3][4096];
    __shared__ float sred[2][3][64];
    const f16* Bb = Bp + (size_t)bidx * bStrideB + (size_t)bn0 * K;

    f32x4 acc[2][2];
    #pragma unroll
    for (int i = 0; i < 2; ++i)
        #pragma unroll
        for (int jj = 0; jj < 2; ++jj) acc[i][jj] = (f32x4)0.f;

#define G1_STAGE(buf, p_) do { \
    const int k0_ = (p_) * 32; \
    _Pragma("unroll") \
    for (int q = 0; q < 2; ++q) { \
        int c_ = w + q * 4; \
        int rq_ = c_ & 3; \
        int row_ = rq_ * 16 + (lane >> 2); \
        int kc_ = (lane & 3) ^ (row_ & 3) ^ ((row_ >> 2) & 3); \
        const f16* src_ = (c_ < 4) ? (A + (size_t)(R0 + row_) * K + k0_ + kc_ * 8) \
                                   : (Bb + (size_t)row_ * K + k0_ + kc_ * 8); \
        gload16(src_, (void*)&lds[buf][(c_ >> 2) * 2048 + rq_ * 512]); \
    } \
} while (0)

    int npan = K >> 5;
    bool skipA = false;
    if (ADJA) {
        int lenb = lens[bidx];
        npan = (lenb + 31) >> 5;          // adj cols >= len are exactly zero
        skipA = ((R0 & (cN - 1)) >= lenb); // adj rows >= len are exactly zero
    }
    if (!skipA) {
        G1_STAGE(0, 0);
        G1_STAGE(1, 1);
        __syncthreads();
        for (int p = 0; p < npan; ++p) {
            int cur = p % 3;
            if (p + 2 < npan) G1_STAGE((p + 2) % 3, p + 2);
            const f16x8* L8 = (const f16x8*)lds[cur];
            f16x8 af[2], bf[2];
            #pragma unroll
            for (int i = 0; i < 2; ++i) {
                int r = wr * 32 + i * 16 + lr;
                int cell = r * 4 + (lc ^ (r & 3) ^ ((r >> 2) & 3));
                af[i] = L8[cell];
            }
            #pragma unroll
            for (int jj = 0; jj < 2; ++jj) {
                int r = wc * 32 + jj * 16 + lr;
                int cell = r * 4 + (lc ^ (r & 3) ^ ((r >> 2) & 3));
                bf[jj] = L8[256 + cell];
            }
            __builtin_amdgcn_s_setprio(1);
            #pragma unroll
            for (int i = 0; i < 2; ++i)
                #pragma unroll
                for (int jj = 0; jj < 2; ++jj)
                    acc[i][jj] = MFMA16(af[i], bf[jj], acc[i][jj]);
            __builtin_amdgcn_s_setprio(0);
            if (p < npan - 1) {
                if (p + 2 < npan) {
                    asm volatile("s_waitcnt vmcnt(2)" ::: "memory");
                } else {
                    asm volatile("s_waitcnt vmcnt(0)" ::: "memory");
                }
                asm volatile("s_waitcnt lgkmcnt(0)" ::: "memory");
                __builtin_amdgcn_s_barrier();
            }
        }
    }
#undef G1_STAGE

    if (OMODE != 2) {
        #pragma unroll
        for (int i = 0; i < 2; ++i)
            #pragma unroll
            for (int jj = 0; jj < 2; ++jj) {
                int col = bn0 + wc * 32 + jj * 16 + lr;
                #pragma unroll
                for (int v = 0; v < 4; ++v) {
                    int r = R0 + wr * 32 + i * 16 + lc * 4 + v;
                    float val = acc[i][jj][v];
                    if (BIAS == 2) val += adjrs[r] * bc1p[col] + biasv[col];
                    if (RELU) val = fmaxf(val, 0.f);
                    size_t addr = (OMODE == 1)
                        ? ((size_t)(r >> 9) * 65536 + (size_t)col * 512 + (r & 511))
                        : ((size_t)r * 128 + col);
                    CH[addr] = (f16)val;
                }
            }
    } else {
        const int b = bidx, rb = (R0 >> 6) & 7, cb = bn0 >> 6;
        int s1 = ments[b * 4 + 0], e1 = ments[b * 4 + 1];
        int s2 = ments[b * 4 + 2], e2 = ments[b * 4 + 3];
        #pragma unroll
        for (int jj = 0; jj < 2; ++jj) {
            int col = bn0 + wc * 32 + jj * 16 + lr;
            float vmax = -INFINITY, v1 = 0.f, v2 = 0.f;
            #pragma unroll
            for (int i = 0; i < 2; ++i)
                #pragma unroll
                for (int v = 0; v < 4; ++v) {
                    int gn = (R0 & 511) + wr * 32 + i * 16 + lc * 4 + v;
                    float val = acc[i][jj][v] + biasv[col];
                    vmax = fmaxf(vmax, val);
                    if (gn >= s1 && gn <= e1) v1 += val;
                    if (gn >= s2 && gn <= e2) v2 += val;
                }
            #pragma unroll
            for (int off = 16; off <= 32; off <<= 1) {
                vmax = fmaxf(vmax, __shfl_xor(vmax, off, 64));
                v1 += __shfl_xor(v1, off, 64);
                v2 += __shfl_xor(v2, off, 64);
            }
            if (lc == 0) {
                int c = wc * 32 + jj * 16 + lr;
                sred[wr][0][c] = vmax;
                sred[wr][1][c] = v1;
                sred[wr][2][c] = v2;
            }
        }
        __syncthreads();
        if (t < 192) {
            int m = t >> 6, c = t & 63;
            float a0 = sred[0][m][c], a1v = sred[1][m][c];
            float comb = (m == 0) ? fmaxf(a0, a1v) : (a0 + a1v);
            part[((((size_t)b * 8 + rb) * 2 + cb) * 3 + m) * 64 + c] = comb;
        }
    }
}

// ---------------- K5b: combine partials + final linear ----------------
__global__ void k_final2(const float* __restrict__ part, const int* __restrict__ mentions,
                         const float* __restrict__ lw, const float* __restrict__ lb,
                         float* __restrict__ out)
{
    int b = blockIdx.x;
    int t = threadIdx.x;   // 128
    __shared__ float vec[128];
    int s1 = mentions[b * 4 + 0], e1 = mentions[b * 4 + 1];
    int s2 = mentions[b * 4 + 2], e2 = mentions[b * 4 + 3];
    int cb = t >> 6, c = t & 63;
    float pm = -INFINITY, s1s = 0.f, s2s = 0.f;
    #pragma unroll
    for (int rb = 0; rb < 8; ++rb) {
        size_t base = ((((size_t)b * 8 + rb) * 2 + cb) * 3) * 64 + c;
        pm = fmaxf(pm, part[base]);
        s1s += part[base + 64];
        s2s += part[base + 128];
    }
    vec[t] = pm + s1s / (float)(e1 - s1 + 1) + s2s / (float)(e2 - s2 + 1);
    __syncthreads();
    if (t < cNREL) {
        float s = lb[t];
        for (int dd = 0; dd < cOUT; ++dd) s += vec[dd] * lw[dd * cNREL + t];
        out[b * cNREL + t] = s;
    }
}

extern "C" void kernel_launch(void* const* d_in, const int* in_sizes, int n_in,
                              void* d_out, int out_size, void* d_ws, size_t ws_size,
                              hipStream_t stream)
{
    const float* context = (const float*)d_in[0];
    const int*   lens    = (const int*)d_in[1];
    const int*   ments   = (const int*)d_in[2];
    const float* w_enc   = (const float*)d_in[3];
    const float* b_enc   = (const float*)d_in[4];
    const float* glw     = (const float*)d_in[5];
    const float* w1      = (const float*)d_in[6];
    const float* b1      = (const float*)d_in[7];
    const float* w2      = (const float*)d_in[8];
    const float* b2      = (const float*)d_in[9];
    const float* lw      = (const float*)d_in[10];
    const float* lb      = (const float*)d_in[11];
    float* out = (float*)d_out;

    // ---- workspace layout (all disjoint) ----
    f16* XH   = (f16*)d_ws;                      // ARRSZ
    f16* XL   = XH + ARRSZ;                      // ARRSZ
    f16* adjH = XL + ARRSZ;                      // NADJ
    f16* E1t  = adjH + NADJ;                     // NE1
    f16* hH   = E1t + NE1;                       // NE1
    f16* H2t  = hH + NE1;                        // NE1
    f16* RAh  = H2t + NE1;                       // NADJ
    float* G0 = (float*)(RAh + NADJ);            // NADJ f32
    float* invnM = G0 + NADJ;                    // NBN*4
    float* maskA = invnM + 4 * NBN;
    float* rinv  = maskA + NBN;
    float* adjrs = rinv + NBN;
    float* part  = adjrs + NBN;                  // 147456
    float* bc1p  = part + 147456;                // 128
    f16* wc1H = (f16*)(bc1p + 128);              // 128*KP
    f16* w2tH = wc1H + (size_t)128 * KP;         // 128*128
    int* kidx = (int*)(w2tH + 128 * 128);        // NBN*10

    k_prep0<<<KP + 1 + NBN / 4, 256, 0, stream>>>(
        context, lens, glw, w_enc, w1, b_enc, w2,
        XH, XL, maskA, invnM, wc1H, bc1p, w2tH);
    k_sim_mfma<<<dim3(8, 8, cB), 256, 0, stream>>>(XH, XL, glw, lens, maskA, invnM, G0, RAh);
    k_topk<<<NBN / 4, 256, 0, stream>>>(G0, maskA, lens, kidx, rinv);
    k_adj2<<<NBN, 256, 0, stream>>>(RAh, rinv, kidx, lens, adjH, adjrs);

    // E1t = (X @ wc1)^T   [b][128][512]
    k_gemm1<0, false, 1, false><<<dim3(NBN / 64, 2), 256, 0, stream>>>(
        XH, wc1H, 0, KP, nullptr, nullptr, nullptr, nullptr, nullptr, E1t, nullptr);
    // h = relu(adj @ E1 + adjrs*bc1p + b1)   [24576][128]
    k_gemm1<2, true, 0, true><<<dim3(NBN / 64, 2), 256, 0, stream>>>(
        adjH, E1t, 65536, cN, lens, b1, bc1p, adjrs, nullptr, hH, nullptr);
    // H2t = (h @ w2)^T   [b][128][512]
    k_gemm1<0, false, 1, false><<<dim3(NBN / 64, 2), 256, 0, stream>>>(
        hH, w2tH, 0, cHID, nullptr, nullptr, nullptr, nullptr, nullptr, H2t, nullptr);
    // nv = adj @ H2 + b2, fused maxpool/mention partials
    k_gemm1<0, false, 2, true><<<dim3(NBN / 64, 2), 256, 0, stream>>>(
        adjH, H2t, 65536, cN, lens, b2, nullptr, nullptr, ments, nullptr, part);

    k_final2<<<cB, 128, 0, stream>>>(part, ments, lw, lb, out);
}

// Round 18
// 183.686 us; speedup vs baseline: 1.3280x; 1.3280x over previous
//
#include <hip/hip_runtime.h>
#include <math.h>

// Problem constants
constexpr int cB = 48, cN = 512, cIN = 400;
constexpr int cENC = 256, cHID = 128, cOUT = 128, cNREL = 53;
constexpr int cKNN = 10;
constexpr float cVSN = 1e-12f;
constexpr float cEPS = 0.3f;

constexpr int KP = 416;                        // cIN padded to multiple of 32
constexpr size_t ARRSZ = (size_t)cB * cN * KP; // elems per f16 array
constexpr int NBN = cB * cN;                   // 24576 rows
constexpr size_t NADJ = (size_t)cB * cN * cN;  // 12,582,912
constexpr size_t NE1 = (size_t)NBN * 128;      // 3,145,728

typedef _Float16 f16;
typedef _Float16 f16x8 __attribute__((ext_vector_type(8)));
typedef float f32x4 __attribute__((ext_vector_type(4)));

__device__ inline void gload16(const void* g, void* l) {
    __builtin_amdgcn_global_load_lds(
        (const __attribute__((address_space(1))) unsigned int*)g,
        (__attribute__((address_space(3))) unsigned int*)l, 16, 0, 0);
}

#define MFMA16(a, b, c) __builtin_amdgcn_mfma_f32_16x16x32_f16((a), (b), (c), 0, 0, 0)

// ---------------- K0a: merged weight prep + streaming split ----------------
// NOTE: do NOT fuse norms into the split waves — reproduced 2x: that fusion
// costs ~98 us (rounds 6/7/17); separate split + norms is ~20 us combined.
__global__ __launch_bounds__(256) void k_prep0(
    const float* __restrict__ X,
    const float* __restrict__ w_enc, const float* __restrict__ w1,
    const float* __restrict__ b_enc, const float* __restrict__ w2,
    f16* __restrict__ XH, f16* __restrict__ XL,
    f16* __restrict__ wc1H, float* __restrict__ bc1p, f16* __restrict__ w2tH)
{
    int bid = blockIdx.x;
    int t = threadIdx.x;
    if (bid <= KP) {
        int d = bid;
        __shared__ float wred[2][128];
        int o = t & 127, half = t >> 7;
        if (d < cIN) {
            float acc = 0.f;
            const float* we = w_enc + (size_t)d * cENC + half * 128;
            const float* w1p = w1 + (size_t)half * 128 * cHID + o;
            #pragma unroll 8
            for (int e = 0; e < 128; ++e) acc += we[e] * w1p[(size_t)e * cHID];
            wred[half][o] = acc;
            __syncthreads();
            if (half == 0) wc1H[(size_t)o * KP + d] = (f16)(wred[0][o] + wred[1][o]);
        } else if (d < KP) {
            if (t < 128) wc1H[(size_t)o * KP + d] = (f16)0.f;
        } else {
            float acc = 0.f;
            const float* w1p = w1 + (size_t)half * 128 * cHID + o;
            #pragma unroll 8
            for (int e = 0; e < 128; ++e) acc += b_enc[half * 128 + e] * w1p[(size_t)e * cHID];
            wred[half][o] = acc;
            __syncthreads();
            if (half == 0) bc1p[o] = wred[0][o] + wred[1][o];
        }
        if (d < cHID && t < 128) w2tH[(size_t)t * cHID + d] = (f16)w2[(size_t)d * cOUT + t];
        return;
    }
    // ---- split part ----
    int row = (bid - (KP + 1)) * 4 + (t >> 6);
    int k8 = t & 63;
    if (k8 >= 52) return;
    size_t obase = (size_t)row * KP + k8 * 8;
    if (k8 < 50) {
        const float* x = X + (size_t)row * cIN + k8 * 8;
        float4 xa = *(const float4*)x;
        float4 xb = *(const float4*)(x + 4);
        float xv[8] = {xa.x, xa.y, xa.z, xa.w, xb.x, xb.y, xb.z, xb.w};
        f16x8 vh, vl;
        #pragma unroll
        for (int e = 0; e < 8; ++e) {
            f16 hh = (f16)xv[e];
            vh[e] = hh;
            vl[e] = (f16)(xv[e] - (float)hh);
        }
        *(f16x8*)(XH + obase) = vh;
        *(f16x8*)(XL + obase) = vl;
    } else {
        f16x8 z = (f16x8)(f16)0.f;
        *(f16x8*)(XH + obase) = z;
        *(f16x8*)(XL + obase) = z;
    }
}

// ---------------- K0c: norms + mask; 1 block per row, 1 wave per perspective ------
__global__ __launch_bounds__(256) void k_norms(const float* __restrict__ X,
                                               const int* __restrict__ lens,
                                               const float* __restrict__ glw,
                                               float* __restrict__ maskA,
                                               float* __restrict__ invnM)
{
    int row = blockIdx.x;
    int t = threadIdx.x;
    int w = t >> 6, lane = t & 63;
    __shared__ float sw[4];
    int b = row >> 9, n = row & (cN - 1);
    float s = 0.f;
    if (lane < 50) {
        int k = lane * 8;
        const float* x = X + (size_t)row * cIN + k;
        const float* g = glw + (size_t)w * cIN + k;
        float4 xa = *(const float4*)x, xb = *(const float4*)(x + 4);
        float4 ga = *(const float4*)g, gb = *(const float4*)(g + 4);
        float xv[8] = {xa.x, xa.y, xa.z, xa.w, xb.x, xb.y, xb.z, xb.w};
        float gv[8] = {ga.x, ga.y, ga.z, ga.w, gb.x, gb.y, gb.z, gb.w};
        #pragma unroll
        for (int e = 0; e < 8; ++e) {
            float tt = xv[e] * gv[e];
            s += tt * tt;
        }
    }
    #pragma unroll
    for (int off = 32; off; off >>= 1) s += __shfl_xor(s, off, 64);
    if (lane == 0) sw[w] = s;
    __syncthreads();
    if (t == 0) {
        float m = (n < lens[b]) ? 1.0f : 0.0f;
        float4 iv;
        iv.x = m / fmaxf(sqrtf(sw[0]), cVSN);
        iv.y = m / fmaxf(sqrtf(sw[1]), cVSN);
        iv.z = m / fmaxf(sqrtf(sw[2]), cVSN);
        iv.w = m / fmaxf(sqrtf(sw[3]), cVSN);
        *(float4*)&invnM[(size_t)row * 4] = iv;
        maskA[row] = m;
    }
}

// ---------------- K1: MFMA similarity; symmetric tiles + XCD-swizzle + 2-buf ------
__global__ __launch_bounds__(256, 3) void k_sim_mfma(
    const f16* __restrict__ XH, const f16* __restrict__ XL,
    const float* __restrict__ glw, const int* __restrict__ lens,
    const float* __restrict__ maskA, const float* __restrict__ invnM,
    float* __restrict__ G0, f16* __restrict__ RAh)
{
    // bijective XCD swizzle: all 64 blocks of a batch on one XCD (L2 holds its X panels)
    int L = blockIdx.x + (blockIdx.y << 3) + (blockIdx.z << 6);
    int xcd = L & 7, j0 = L >> 3;
    int work = xcd * 384 + j0;
    const int b = work >> 6;
    int rem = work & 63;
    const int n0 = (rem >> 3) * 64, m0 = (rem & 7) * 64;

    const int t = threadIdx.x;
    const int w = t >> 6, lane = t & 63;
    const int wr = w >> 1, wc = w & 1;
    const int lr = lane & 15, lc = lane >> 4;

    const size_t rowBaseB = (size_t)b * cN;
    const int len = lens[b];

    // symmetry: only tiles with n0 <= m0; masked tiles: pure no-op
    if (n0 >= len || m0 >= len || n0 > m0) return;

    __shared__ f16 lds[2][8192];   // 2 bufs x 4 tiles x [64 rows][4 slots][8 f16]
    __shared__ f16 w2l[4][KP];

    for (int i = t; i < 4 * KP; i += 256) {
        int p = i / KP, d = i - p * KP;
        float g = (d < cIN) ? glw[p * cIN + d] : 0.f;
        w2l[p][d] = (f16)(g * g);
    }

    f32x4 accG[2][2], accP[4][2][2];
    #pragma unroll
    for (int i = 0; i < 2; ++i)
        #pragma unroll
        for (int jj = 0; jj < 2; ++jj) {
            accG[i][jj] = (f32x4)0.f;
            #pragma unroll
            for (int p = 0; p < 4; ++p) accP[p][i][jj] = (f32x4)0.f;
        }

    constexpr int NPAN = KP / 32;    // 13

    // tiles: 0 = XH@n0, 1 = XL@n0, 2 = XH@m0, 3 = XL@m0; 4 gloads per wave per panel
#define SIM_STAGE(buf, pan) do { \
    const int kk0_ = (pan) * 32; \
    _Pragma("unroll") \
    for (int q = 0; q < 4; ++q) { \
        int c_ = w + q * 4;               /* chunk 0..15, wave-uniform */ \
        int tt_ = c_ >> 2, rq_ = c_ & 3; \
        int row_ = rq_ * 16 + (lane >> 2); \
        int kcg_ = (lane & 3) ^ (row_ & 3) ^ ((row_ >> 2) & 3); \
        const f16* arr_ = (tt_ & 1) ? XL : XH; \
        int rb_ = (tt_ < 2) ? n0 : m0; \
        const f16* g_ = arr_ + (rowBaseB + rb_ + row_) * (size_t)KP + kk0_ + kcg_ * 8; \
        gload16(g_, (void*)&lds[buf][tt_ * 2048 + rq_ * 512]); \
    } \
} while (0)

    SIM_STAGE(0, 0);
    __syncthreads();

    for (int pan = 0; pan < NPAN; ++pan) {
        int cur = pan & 1;
        if (pan + 1 < NPAN) SIM_STAGE(cur ^ 1, pan + 1);
        const f16x8* L8 = (const f16x8*)lds[cur];
        const int kk0 = pan * 32;
        f16x8 aH[2], aL[2], bH[2], bL[2], wp[4];
        #pragma unroll
        for (int i = 0; i < 2; ++i) {
            int r = wr * 32 + i * 16 + lr;
            int cell = r * 4 + (lc ^ (r & 3) ^ ((r >> 2) & 3));
            aH[i] = L8[cell];
            aL[i] = L8[256 + cell];
        }
        #pragma unroll
        for (int jj = 0; jj < 2; ++jj) {
            int r = wc * 32 + jj * 16 + lr;
            int cell = r * 4 + (lc ^ (r & 3) ^ ((r >> 2) & 3));
            bH[jj] = L8[512 + cell];
            bL[jj] = L8[768 + cell];
        }
        #pragma unroll
        for (int p = 0; p < 4; ++p) wp[p] = *(const f16x8*)&w2l[p][kk0 + lc * 8];

        __builtin_amdgcn_s_setprio(1);
        #pragma unroll
        for (int i = 0; i < 2; ++i)
            #pragma unroll
            for (int jj = 0; jj < 2; ++jj) {
                accG[i][jj] = MFMA16(aH[i], bH[jj], accG[i][jj]);
                accG[i][jj] = MFMA16(aH[i], bL[jj], accG[i][jj]);
                accG[i][jj] = MFMA16(aL[i], bH[jj], accG[i][jj]);
            }
        #pragma unroll
        for (int p = 0; p < 4; ++p)
            #pragma unroll
            for (int i = 0; i < 2; ++i) {
                f16x8 ap = aH[i] * wp[p];
                #pragma unroll
                for (int jj = 0; jj < 2; ++jj)
                    accP[p][i][jj] = MFMA16(ap, bH[jj], accP[p][i][jj]);
            }
        __builtin_amdgcn_s_setprio(0);
        __syncthreads();
    }
#undef SIM_STAGE

    // ---- epilogue: normalize, direct store; off-diag also stash for transpose ----
    float* sG = (float*)lds;             // [64][65] f32 = 16.6 KB
    f16*   sR = (f16*)((float*)lds + 64 * 65);  // [64][66] f16 = 8.4 KB  (25 KB <= 32 KB)
    const bool offdiag = (n0 != m0);

    #pragma unroll
    for (int i = 0; i < 2; ++i) {
        #pragma unroll
        for (int jj = 0; jj < 2; ++jj) {
            int ml = wc * 32 + jj * 16 + lr;
            int m = m0 + ml;
            size_t rowm = rowBaseB + m;
            float mskm = maskA[rowm];
            float4 im = *(const float4*)&invnM[rowm * 4];
            #pragma unroll
            for (int v = 0; v < 4; ++v) {
                int nl = wr * 32 + i * 16 + lc * 4 + v;
                size_t rown = rowBaseB + n0 + nl;
                float4 in_ = *(const float4*)&invnM[rown * 4];
                float g = accG[i][jj][v] * maskA[rown] * mskm;
                float s = 0.25f * (accP[0][i][jj][v] * in_.x * im.x
                                 + accP[1][i][jj][v] * in_.y * im.y
                                 + accP[2][i][jj][v] * in_.z * im.z
                                 + accP[3][i][jj][v] * in_.w * im.w);
                float rv = (s > cEPS) ? s : 0.f;
                __builtin_nontemporal_store(g, &G0[rown * cN + m]);
                RAh[rown * cN + m] = (f16)rv;
                if (offdiag) {
                    sG[nl * 65 + ml] = g;
                    sR[nl * 66 + ml] = (f16)rv;
                }
            }
        }
    }
    if (offdiag) {
        __syncthreads();
        // transpose-copy: G0[m][n] = G0[n][m], RA likewise (both symmetric)
        #pragma unroll
        for (int e = 0; e < 16; ++e) {
            int idx = t + e * 256;          // 0..4095
            int mr = idx >> 6, nc = idx & 63;
            size_t rowm = rowBaseB + m0 + mr;
            float gv = sG[nc * 65 + mr];
            f16 rvv = sR[nc * 66 + mr];
            __builtin_nontemporal_store(gv, &G0[rowm * cN + n0 + nc]);
            RAh[rowm * cN + n0 + nc] = rvv;
        }
    }
}

// ---------------- K2: per-row top-10, value-only; len-trimmed reads ----------------
__global__ void k_topk(const float* __restrict__ G0, const float* __restrict__ mask,
                       const int* __restrict__ lens,
                       int* __restrict__ kidx, float* __restrict__ rinv)
{
    int row = blockIdx.x * 4 + (threadIdx.x >> 6);
    int lane = threadIdx.x & 63;
    int b = row >> 9, n = row & (cN - 1);
    int len = lens[b];
    if (n >= len) {
        if (lane < cKNN) kidx[row * cKNN + lane] = lane;
        if (lane == 0) rinv[row] = 0.f;
        return;
    }
    int lenc = (len + 63) & ~63;
    const float* g = G0 + (long long)row * cN;
    float val[8];
    #pragma unroll
    for (int k = 0; k < 8; ++k) {
        int col = lane + 64 * k;
        val[k] = (col < lenc) ? __builtin_nontemporal_load(&g[col]) : -INFINITY;
    }
    float cnt = 0.f;
    long long mbase = (long long)b * cN;
    for (int r = 0; r < cKNN; ++r) {
        float best = val[0];
        #pragma unroll
        for (int k = 1; k < 8; ++k) best = fmaxf(best, val[k]);
        #pragma unroll
        for (int off = 32; off; off >>= 1) best = fmaxf(best, __shfl_xor(best, off, 64));
        int sl = -1;
        #pragma unroll
        for (int k = 7; k >= 0; --k) if (val[k] == best) sl = k;
        unsigned long long holders = __ballot(sl >= 0);
        int src = (int)(__ffsll((long long)holders) - 1);
        int mycol = lane + (sl << 6);
        int col = __shfl(mycol, src, 64);
        if (lane == src) val[sl] = -INFINITY;
        if (lane == 0) {
            kidx[row * cKNN + r] = col;
            cnt += mask[mbase + col];
        }
    }
    if (lane == 0) rinv[row] = rsqrtf(fmaxf(cnt, cVSN));
}

// ---------------- K3: adjacency assembly; masked rows/cols exact-zero paths --------
__global__ void k_adj2(const f16* __restrict__ RAh, const float* __restrict__ rinv,
                       const int* __restrict__ kidx, const int* __restrict__ lens,
                       f16* __restrict__ adjH, float* __restrict__ adjrs)
{
    int row = blockIdx.x;
    int t = threadIdx.x;  // 256
    int b = row >> 9, n = row & (cN - 1);
    int len = lens[b];
    long long base = (long long)row * cN;
    if (n >= len) {
        adjH[base + t] = (f16)0.f;
        adjH[base + t + 256] = (f16)0.f;
        if (t == 0) adjrs[row] = 0.f;
        return;
    }
    int w = t >> 6, lane = t & 63;
    __shared__ int sidx[cKNN];
    __shared__ float srv[cKNN];
    __shared__ float red[4];
    long long bbase = (long long)(row & ~(cN - 1));
    if (t < cKNN) {
        int c = kidx[row * cKNN + t];
        sidx[t] = c;
        srv[t] = rinv[bbase + c];
    }
    float ra0 = (t < len) ? (float)RAh[base + t] : 0.f;
    float ra1 = (t + 256 < len) ? (float)RAh[base + t + 256] : 0.f;
    float s = ra0 + ra1;
    #pragma unroll
    for (int off = 32; off; off >>= 1) s += __shfl_xor(s, off, 64);
    if (lane == 0) red[w] = s;
    __syncthreads();
    float rsum = red[0] + red[1] + red[2] + red[3];
    float inv_rs = 1.0f / fmaxf(rsum, cVSN);
    float rn = rinv[row];
    float osum = 0.f;
    #pragma unroll
    for (int mi = 0; mi < 2; ++mi) {
        int m = t + mi * 256;
        float ra = mi ? ra1 : ra0;
        float v = 0.2f * ra * inv_rs;
        #pragma unroll
        for (int k = 0; k < cKNN; ++k)
            if (m == sidx[k]) v += 0.8f * rn * srv[k];
        adjH[base + m] = (f16)v;
        osum += v;
    }
    #pragma unroll
    for (int off = 32; off; off >>= 1) osum += __shfl_xor(osum, off, 64);
    __syncthreads();
    if (lane == 0) red[w] = osum;
    __syncthreads();
    if (t == 0) adjrs[row] = red[0] + red[1] + red[2] + red[3];
}

// ---------------- Single-pass f16 MFMA GEMM; ADJA enables mask-driven trimming ----
template<int BIAS, bool RELU, int OMODE, bool ADJA>
__global__ __launch_bounds__(256, 4) void k_gemm1(
    const f16* __restrict__ A, const f16* __restrict__ Bp,
    long long bStrideB, int K, const int* __restrict__ lens,
    const float* __restrict__ biasv, const float* __restrict__ bc1p,
    const float* __restrict__ adjrs, const int* __restrict__ ments,
    f16* __restrict__ CH, float* __restrict__ part)
{
    int L = blockIdx.x + blockIdx.y * gridDim.x;
    int work = (L & 7) * 96 + (L >> 3);
    const int R0 = (work >> 1) * 64;
    const int bn0 = (work & 1) * 64;
    const int bidx = R0 >> 9;
    const int t = threadIdx.x, w = t >> 6, lane = t & 63;
    const int wr = w >> 1, wc = w & 1, lr = lane & 15, lc = lane >> 4;
    __shared__ f16 lds[3][4096];
    __shared__ float sred[2][3][64];
    const f16* Bb = Bp + (size_t)bidx * bStrideB + (size_t)bn0 * K;

    f32x4 acc[2][2];
    #pragma unroll
    for (int i = 0; i < 2; ++i)
        #pragma unroll
        for (int jj = 0; jj < 2; ++jj) acc[i][jj] = (f32x4)0.f;

#define G1_STAGE(buf, p_) do { \
    const int k0_ = (p_) * 32; \
    _Pragma("unroll") \
    for (int q = 0; q < 2; ++q) { \
        int c_ = w + q * 4; \
        int rq_ = c_ & 3; \
        int row_ = rq_ * 16 + (lane >> 2); \
        int kc_ = (lane & 3) ^ (row_ & 3) ^ ((row_ >> 2) & 3); \
        const f16* src_ = (c_ < 4) ? (A + (size_t)(R0 + row_) * K + k0_ + kc_ * 8) \
                                   : (Bb + (size_t)row_ * K + k0_ + kc_ * 8); \
        gload16(src_, (void*)&lds[buf][(c_ >> 2) * 2048 + rq_ * 512]); \
    } \
} while (0)

    int npan = K >> 5;
    bool skipA = false;
    if (ADJA) {
        int lenb = lens[bidx];
        npan = (lenb + 31) >> 5;          // adj cols >= len are exactly zero
        skipA = ((R0 & (cN - 1)) >= lenb); // adj rows >= len are exactly zero
    }
    if (!skipA) {
        G1_STAGE(0, 0);
        G1_STAGE(1, 1);
        __syncthreads();
        for (int p = 0; p < npan; ++p) {
            int cur = p % 3;
            if (p + 2 < npan) G1_STAGE((p + 2) % 3, p + 2);
            const f16x8* L8 = (const f16x8*)lds[cur];
            f16x8 af[2], bf[2];
            #pragma unroll
            for (int i = 0; i < 2; ++i) {
                int r = wr * 32 + i * 16 + lr;
                int cell = r * 4 + (lc ^ (r & 3) ^ ((r >> 2) & 3));
                af[i] = L8[cell];
            }
            #pragma unroll
            for (int jj = 0; jj < 2; ++jj) {
                int r = wc * 32 + jj * 16 + lr;
                int cell = r * 4 + (lc ^ (r & 3) ^ ((r >> 2) & 3));
                bf[jj] = L8[256 + cell];
            }
            __builtin_amdgcn_s_setprio(1);
            #pragma unroll
            for (int i = 0; i < 2; ++i)
                #pragma unroll
                for (int jj = 0; jj < 2; ++jj)
                    acc[i][jj] = MFMA16(af[i], bf[jj], acc[i][jj]);
            __builtin_amdgcn_s_setprio(0);
            if (p < npan - 1) {
                if (p + 2 < npan) {
                    asm volatile("s_waitcnt vmcnt(2)" ::: "memory");
                } else {
                    asm volatile("s_waitcnt vmcnt(0)" ::: "memory");
                }
                asm volatile("s_waitcnt lgkmcnt(0)" ::: "memory");
                __builtin_amdgcn_s_barrier();
            }
        }
    }
#undef G1_STAGE

    if (OMODE != 2) {
        #pragma unroll
        for (int i = 0; i < 2; ++i)
            #pragma unroll
            for (int jj = 0; jj < 2; ++jj) {
                int col = bn0 + wc * 32 + jj * 16 + lr;
                #pragma unroll
                for (int v = 0; v < 4; ++v) {
                    int r = R0 + wr * 32 + i * 16 + lc * 4 + v;
                    float val = acc[i][jj][v];
                    if (BIAS == 2) val += adjrs[r] * bc1p[col] + biasv[col];
                    if (RELU) val = fmaxf(val, 0.f);
                    size_t addr = (OMODE == 1)
                        ? ((size_t)(r >> 9) * 65536 + (size_t)col * 512 + (r & 511))
                        : ((size_t)r * 128 + col);
                    CH[addr] = (f16)val;
                }
            }
    } else {
        const int b = bidx, rb = (R0 >> 6) & 7, cb = bn0 >> 6;
        int s1 = ments[b * 4 + 0], e1 = ments[b * 4 + 1];
        int s2 = ments[b * 4 + 2], e2 = ments[b * 4 + 3];
        #pragma unroll
        for (int jj = 0; jj < 2; ++jj) {
            int col = bn0 + wc * 32 + jj * 16 + lr;
            float vmax = -INFINITY, v1 = 0.f, v2 = 0.f;
            #pragma unroll
            for (int i = 0; i < 2; ++i)
                #pragma unroll
                for (int v = 0; v < 4; ++v) {
                    int gn = (R0 & 511) + wr * 32 + i * 16 + lc * 4 + v;
                    float val = acc[i][jj][v] + biasv[col];
                    vmax = fmaxf(vmax, val);
                    if (gn >= s1 && gn <= e1) v1 += val;
                    if (gn >= s2 && gn <= e2) v2 += val;
                }
            #pragma unroll
            for (int off = 16; off <= 32; off <<= 1) {
                vmax = fmaxf(vmax, __shfl_xor(vmax, off, 64));
                v1 += __shfl_xor(v1, off, 64);
                v2 += __shfl_xor(v2, off, 64);
            }
            if (lc == 0) {
                int c = wc * 32 + jj * 16 + lr;
                sred[wr][0][c] = vmax;
                sred[wr][1][c] = v1;
                sred[wr][2][c] = v2;
            }
        }
        __syncthreads();
        if (t < 192) {
            int m = t >> 6, c = t & 63;
            float a0 = sred[0][m][c], a1v = sred[1][m][c];
            float comb = (m == 0) ? fmaxf(a0, a1v) : (a0 + a1v);
            part[((((size_t)b * 8 + rb) * 2 + cb) * 3 + m) * 64 + c] = comb;
        }
    }
}

// ---------------- K5b: combine partials + final linear ----------------
__global__ void k_final2(const float* __restrict__ part, const int* __restrict__ mentions,
                         const float* __restrict__ lw, const float* __restrict__ lb,
                         float* __restrict__ out)
{
    int b = blockIdx.x;
    int t = threadIdx.x;   // 128
    __shared__ float vec[128];
    int s1 = mentions[b * 4 + 0], e1 = mentions[b * 4 + 1];
    int s2 = mentions[b * 4 + 2], e2 = mentions[b * 4 + 3];
    int cb = t >> 6, c = t & 63;
    float pm = -INFINITY, s1s = 0.f, s2s = 0.f;
    #pragma unroll
    for (int rb = 0; rb < 8; ++rb) {
        size_t base = ((((size_t)b * 8 + rb) * 2 + cb) * 3) * 64 + c;
        pm = fmaxf(pm, part[base]);
        s1s += part[base + 64];
        s2s += part[base + 128];
    }
    vec[t] = pm + s1s / (float)(e1 - s1 + 1) + s2s / (float)(e2 - s2 + 1);
    __syncthreads();
    if (t < cNREL) {
        float s = lb[t];
        for (int dd = 0; dd < cOUT; ++dd) s += vec[dd] * lw[dd * cNREL + t];
        out[b * cNREL + t] = s;
    }
}

extern "C" void kernel_launch(void* const* d_in, const int* in_sizes, int n_in,
                              void* d_out, int out_size, void* d_ws, size_t ws_size,
                              hipStream_t stream)
{
    const float* context = (const float*)d_in[0];
    const int*   lens    = (const int*)d_in[1];
    const int*   ments   = (const int*)d_in[2];
    const float* w_enc   = (const float*)d_in[3];
    const float* b_enc   = (const float*)d_in[4];
    const float* glw     = (const float*)d_in[5];
    const float* w1      = (const float*)d_in[6];
    const float* b1      = (const float*)d_in[7];
    const float* w2      = (const float*)d_in[8];
    const float* b2      = (const float*)d_in[9];
    const float* lw      = (const float*)d_in[10];
    const float* lb      = (const float*)d_in[11];
    float* out = (float*)d_out;

    // ---- workspace layout (all disjoint) ----
    f16* XH   = (f16*)d_ws;                      // ARRSZ
    f16* XL   = XH + ARRSZ;                      // ARRSZ
    f16* adjH = XL + ARRSZ;                      // NADJ
    f16* E1t  = adjH + NADJ;                     // NE1
    f16* hH   = E1t + NE1;                       // NE1
    f16* H2t  = hH + NE1;                        // NE1
    f16* RAh  = H2t + NE1;                       // NADJ
    float* G0 = (float*)(RAh + NADJ);            // NADJ f32
    float* invnM = G0 + NADJ;                    // NBN*4
    float* maskA = invnM + 4 * NBN;
    float* rinv  = maskA + NBN;
    float* adjrs = rinv + NBN;
    float* part  = adjrs + NBN;                  // 147456
    float* bc1p  = part + 147456;                // 128
    f16* wc1H = (f16*)(bc1p + 128);              // 128*KP
    f16* w2tH = wc1H + (size_t)128 * KP;         // 128*128
    int* kidx = (int*)(w2tH + 128 * 128);        // NBN*10

    k_prep0<<<KP + 1 + NBN / 4, 256, 0, stream>>>(
        context, w_enc, w1, b_enc, w2, XH, XL, wc1H, bc1p, w2tH);
    k_norms<<<NBN, 256, 0, stream>>>(context, lens, glw, maskA, invnM);
    k_sim_mfma<<<dim3(8, 8, cB), 256, 0, stream>>>(XH, XL, glw, lens, maskA, invnM, G0, RAh);
    k_topk<<<NBN / 4, 256, 0, stream>>>(G0, maskA, lens, kidx, rinv);
    k_adj2<<<NBN, 256, 0, stream>>>(RAh, rinv, kidx, lens, adjH, adjrs);

    // E1t = (X @ wc1)^T   [b][128][512]
    k_gemm1<0, false, 1, false><<<dim3(NBN / 64, 2), 256, 0, stream>>>(
        XH, wc1H, 0, KP, nullptr, nullptr, nullptr, nullptr, nullptr, E1t, nullptr);
    // h = relu(adj @ E1 + adjrs*bc1p + b1)   [24576][128]
    k_gemm1<2, true, 0, true><<<dim3(NBN / 64, 2), 256, 0, stream>>>(
        adjH, E1t, 65536, cN, lens, b1, bc1p, adjrs, nullptr, hH, nullptr);
    // H2t = (h @ w2)^T   [b][128][512]
    k_gemm1<0, false, 1, false><<<dim3(NBN / 64, 2), 256, 0, stream>>>(
        hH, w2tH, 0, cHID, nullptr, nullptr, nullptr, nullptr, nullptr, H2t, nullptr);
    // nv = adj @ H2 + b2, fused maxpool/mention partials
    k_gemm1<0, false, 2, true><<<dim3(NBN / 64, 2), 256, 0, stream>>>(
        adjH, H2t, 65536, cN, lens, b2, nullptr, nullptr, ments, nullptr, part);

    k_final2<<<cB, 128, 0, stream>>>(part, ments, lw, lb, out);
}